// Round 1
// baseline (1103.694 us; speedup 1.0000x reference)
//
#include <hip/hip_runtime.h>
#include <hip/hip_bf16.h>

// Problem: N=4096, Dx=512, Dz=64.
// out[0]=total, out[1]=rank_loss, out[2]=pairdist_loss (f32).
//
// Pipeline:
//   1. prep: nx[i]=sum x[i]^2 (f32), nz likewise; cast x,z to bf16.
//   2. gram_dist (bf16 MFMA): dist = sqrt(max(n_i + n_j - 2*(A A^T)_ij, 0)),
//      diag forced to 0. Written to ws as f32 [4096][4096], for x and z.
//   3. rank kernel: one block per row; bitonic-sort (distbits<<32)|col keys
//      in LDS for x-row -> ranks (u16 LDS), then z-row; accumulate
//      sum|rank_x - rank_z| (u64 atomic) and sum (dz-dx)^2 (double atomic).
//   4. finalize: 3 scalars.

#define N 4096
#define DX 512
#define DZ 64

typedef __attribute__((ext_vector_type(8))) short short8;
typedef __attribute__((ext_vector_type(4))) float float4v;
typedef __attribute__((ext_vector_type(4))) int int4v;

// ---------------- prep: norms + bf16 casts ----------------
__global__ __launch_bounds__(256) void prep_kernel(
    const float* __restrict__ x, const float* __restrict__ z,
    __hip_bfloat16* __restrict__ xb, __hip_bfloat16* __restrict__ zb,
    float* __restrict__ nx, float* __restrict__ nz) {
  int row = blockIdx.x;
  int tid = threadIdx.x;
  __shared__ float red[256];

  float sx = 0.f;
  for (int c = tid; c < DX; c += 256) {
    float v = x[(size_t)row * DX + c];
    xb[(size_t)row * DX + c] = __float2bfloat16(v);
    sx += v * v;
  }
  red[tid] = sx;
  __syncthreads();
  for (int s = 128; s > 0; s >>= 1) {
    if (tid < s) red[tid] += red[tid + s];
    __syncthreads();
  }
  if (tid == 0) nx[row] = red[0];
  __syncthreads();

  float sz = 0.f;
  if (tid < DZ) {
    float v = z[(size_t)row * DZ + tid];
    zb[(size_t)row * DZ + tid] = __float2bfloat16(v);
    sz = v * v;
  }
  red[tid] = sz;
  __syncthreads();
  for (int s = 128; s > 0; s >>= 1) {
    if (tid < s) red[tid] += red[tid + s];
    __syncthreads();
  }
  if (tid == 0) nz[row] = red[0];
}

// ---------------- bf16 MFMA Gram + distance epilogue ----------------
// C = A * A^T over K, tile 128x128 per 256-thread block (4 waves in 2x2),
// each wave computes 64x64 via 4x4 grid of 16x16x32 bf16 MFMAs.
#define TILE 128
#define BK 32
#define LDSPAD 8  // pad row to 40 shorts (80B) to spread banks

__global__ __launch_bounds__(256) void gram_dist_kernel(
    const __hip_bfloat16* __restrict__ Abf,  // [N][K] row-major
    const float* __restrict__ norms,         // [N]
    float* __restrict__ dist,                // [N][N]
    int K) {
  __shared__ short As[TILE][BK + LDSPAD];
  __shared__ short Bs[TILE][BK + LDSPAD];

  int tid = threadIdx.x;
  int wave = tid >> 6, lane = tid & 63;
  int wr = wave >> 1, wc = wave & 1;
  int quad = lane >> 4, l15 = lane & 15;

  int rowBase = blockIdx.y * TILE;
  int colBase = blockIdx.x * TILE;

  float4v acc[4][4];
#pragma unroll
  for (int mi = 0; mi < 4; ++mi)
#pragma unroll
    for (int ni = 0; ni < 4; ++ni) {
      float4v zv = {0.f, 0.f, 0.f, 0.f};
      acc[mi][ni] = zv;
    }

  const short* A16 = (const short*)Abf;

  for (int kc = 0; kc < K; kc += BK) {
    // stage A and B tiles: 128 rows x 32 cols each, 16B per load
#pragma unroll
    for (int g = tid; g < 512; g += 256) {
      int r = g >> 2;
      int c8 = (g & 3) * 8;
      const int4v* srcA =
          (const int4v*)(A16 + (size_t)(rowBase + r) * K + kc + c8);
      *(int4v*)(&As[r][c8]) = *srcA;
      const int4v* srcB =
          (const int4v*)(A16 + (size_t)(colBase + r) * K + kc + c8);
      *(int4v*)(&Bs[r][c8]) = *srcB;
    }
    __syncthreads();

    short8 a[4], b[4];
#pragma unroll
    for (int mi = 0; mi < 4; ++mi)
      a[mi] = *(const short8*)(&As[wr * 64 + mi * 16 + l15][quad * 8]);
#pragma unroll
    for (int ni = 0; ni < 4; ++ni)
      b[ni] = *(const short8*)(&Bs[wc * 64 + ni * 16 + l15][quad * 8]);
#pragma unroll
    for (int mi = 0; mi < 4; ++mi)
#pragma unroll
      for (int ni = 0; ni < 4; ++ni)
        acc[mi][ni] = __builtin_amdgcn_mfma_f32_16x16x32_bf16(
            a[mi], b[ni], acc[mi][ni], 0, 0, 0);
    __syncthreads();
  }

  // epilogue: dist = sqrt(max(n_row + n_col - 2*gram, 0)), diag = 0
#pragma unroll
  for (int mi = 0; mi < 4; ++mi) {
#pragma unroll
    for (int ni = 0; ni < 4; ++ni) {
      int col = colBase + wc * 64 + ni * 16 + l15;
      float ncol = norms[col];
#pragma unroll
      for (int r = 0; r < 4; ++r) {
        int row = rowBase + wr * 64 + mi * 16 + quad * 4 + r;
        float sq = norms[row] + ncol - 2.0f * acc[mi][ni][r];
        float d = sq > 0.f ? sqrtf(sq) : 0.f;
        if (row == col) d = 0.f;
        dist[(size_t)row * N + col] = d;
      }
    }
  }
}

// ---------------- per-row ranking via bitonic sort ----------------
__device__ inline void bitonic_sort_4096(unsigned long long* keys, int tid) {
  for (int k = 2; k <= 4096; k <<= 1) {
    for (int j = k >> 1; j > 0; j >>= 1) {
#pragma unroll 1
      for (int c = tid; c < 2048; c += 256) {
        int i = ((c & ~(j - 1)) << 1) | (c & (j - 1));
        int l = i | j;
        unsigned long long a = keys[i];
        unsigned long long b = keys[l];
        bool doswap = (a > b) == ((i & k) == 0);
        if (doswap) {
          keys[i] = b;
          keys[l] = a;
        }
      }
      __syncthreads();
    }
  }
}

__global__ __launch_bounds__(256) void rank_kernel(
    const float* __restrict__ distx, const float* __restrict__ distz,
    unsigned long long* __restrict__ rank_acc, double* __restrict__ pd_acc) {
  __shared__ unsigned long long keys[N];
  __shared__ unsigned short rankx[N];
  __shared__ int redI[256];
  __shared__ float redF[256];

  int row = blockIdx.x;
  int tid = threadIdx.x;
  const float* dxr = distx + (size_t)row * N;
  const float* dzr = distz + (size_t)row * N;

  float pd = 0.f;
  for (int j = tid; j < N; j += 256) {
    float dx = dxr[j];
    float dz = dzr[j];
    float df = dz - dx;
    pd += df * df;
    keys[j] = ((unsigned long long)__float_as_uint(dx) << 32) |
              (unsigned long long)j;
  }
  __syncthreads();

  bitonic_sort_4096(keys, tid);

  for (int p = tid; p < N; p += 256) {
    int idx = (int)(keys[p] & 0xFFFFFFFFull);
    rankx[idx] = (unsigned short)p;
  }
  __syncthreads();

  for (int j = tid; j < N; j += 256) {
    keys[j] = ((unsigned long long)__float_as_uint(dzr[j]) << 32) |
              (unsigned long long)j;
  }
  __syncthreads();

  bitonic_sort_4096(keys, tid);

  int rsum = 0;
  for (int p = tid; p < N; p += 256) {
    int idx = (int)(keys[p] & 0xFFFFFFFFull);
    int rx = (int)rankx[idx];
    int d = rx - p;
    rsum += d < 0 ? -d : d;
  }

  redI[tid] = rsum;
  redF[tid] = pd;
  __syncthreads();
  for (int s = 128; s > 0; s >>= 1) {
    if (tid < s) {
      redI[tid] += redI[tid + s];
      redF[tid] += redF[tid + s];
    }
    __syncthreads();
  }
  if (tid == 0) {
    atomicAdd(rank_acc, (unsigned long long)redI[0]);
    atomicAdd(pd_acc, (double)redF[0]);
  }
}

// ---------------- finalize ----------------
__global__ void finalize_kernel(const unsigned long long* __restrict__ racc,
                                const double* __restrict__ pacc,
                                float* __restrict__ out) {
  double inv = 1.0 / ((double)N * (double)N);
  double rank_loss = (double)(*racc) * inv / 32.0;  // K = 32
  double pd = (*pacc) * inv;
  out[0] = (float)(rank_loss + 0.5 * pd);
  out[1] = (float)rank_loss;
  out[2] = (float)pd;
}

// ---------------- launch ----------------
extern "C" void kernel_launch(void* const* d_in, const int* in_sizes, int n_in,
                              void* d_out, int out_size, void* d_ws,
                              size_t ws_size, hipStream_t stream) {
  (void)in_sizes; (void)n_in; (void)out_size; (void)ws_size;
  const float* x = (const float*)d_in[0];
  const float* z = (const float*)d_in[1];
  float* out = (float*)d_out;

  char* w = (char*)d_ws;
  float* dist_x = (float*)(w);                                   // 64 MB
  float* dist_z = (float*)(w + 67108864);                        // 64 MB
  __hip_bfloat16* xb = (__hip_bfloat16*)(w + 134217728);         // 4 MB
  __hip_bfloat16* zb = (__hip_bfloat16*)(w + 138412032);         // 0.5 MB
  float* nx = (float*)(w + 138936320);                           // 16 KB
  float* nz = (float*)(w + 138952704);                           // 16 KB
  unsigned long long* rank_acc = (unsigned long long*)(w + 138969088);
  double* pd_acc = (double*)(w + 138969096);

  hipMemsetAsync(w + 138969088, 0, 16, stream);

  prep_kernel<<<N, 256, 0, stream>>>(x, z, xb, zb, nx, nz);

  dim3 ggrid(N / TILE, N / TILE);
  gram_dist_kernel<<<ggrid, 256, 0, stream>>>(xb, nx, dist_x, DX);
  gram_dist_kernel<<<ggrid, 256, 0, stream>>>(zb, nz, dist_z, DZ);

  rank_kernel<<<N, 256, 0, stream>>>(dist_x, dist_z, rank_acc, pd_acc);

  finalize_kernel<<<1, 1, 0, stream>>>(rank_acc, pd_acc, out);
}

// Round 2
// 322.182 us; speedup vs baseline: 3.4257x; 3.4257x over previous
//
#include <hip/hip_runtime.h>
#include <hip/hip_bf16.h>

// Problem: N=4096, Dx=512, Dz=64.
// out[0]=total, out[1]=rank_loss, out[2]=pairdist_loss (f32).
//
// Pipeline:
//   1. prep: nx[i]=sum x[i]^2 (f32), nz likewise; cast x,z to bf16.
//   2. gram_dist (bf16 MFMA): dist = sqrt(max(n_i + n_j - 2*(A A^T)_ij, 0)).
//   3. rank kernel: one block per row; stable 4-pass 4-bit LSD radix sort on
//      (q16_dist << 12) | col packed u32 keys; ranks via scatter position.
//      Quantization: q16 = floor(d * 65536/bound), bound 64 (x) / 32 (z).
//      Collisions only cause index-order tie-breaks (~1e-2 loss noise).
//   4. finalize: 3 scalars.

#define N 4096
#define DX 512
#define DZ 64

typedef __attribute__((ext_vector_type(8))) short short8;
typedef __attribute__((ext_vector_type(4))) float float4v;
typedef __attribute__((ext_vector_type(4))) int int4v;

// ---------------- prep: norms + bf16 casts ----------------
__global__ __launch_bounds__(256) void prep_kernel(
    const float* __restrict__ x, const float* __restrict__ z,
    __hip_bfloat16* __restrict__ xb, __hip_bfloat16* __restrict__ zb,
    float* __restrict__ nx, float* __restrict__ nz) {
  int row = blockIdx.x;
  int tid = threadIdx.x;
  __shared__ float red[256];

  float sx = 0.f;
  for (int c = tid; c < DX; c += 256) {
    float v = x[(size_t)row * DX + c];
    xb[(size_t)row * DX + c] = __float2bfloat16(v);
    sx += v * v;
  }
  red[tid] = sx;
  __syncthreads();
  for (int s = 128; s > 0; s >>= 1) {
    if (tid < s) red[tid] += red[tid + s];
    __syncthreads();
  }
  if (tid == 0) nx[row] = red[0];
  __syncthreads();

  float sz = 0.f;
  if (tid < DZ) {
    float v = z[(size_t)row * DZ + tid];
    zb[(size_t)row * DZ + tid] = __float2bfloat16(v);
    sz = v * v;
  }
  red[tid] = sz;
  __syncthreads();
  for (int s = 128; s > 0; s >>= 1) {
    if (tid < s) red[tid] += red[tid + s];
    __syncthreads();
  }
  if (tid == 0) nz[row] = red[0];
}

// ---------------- bf16 MFMA Gram + distance epilogue ----------------
#define TILE 128
#define BK 32
#define LDSPAD 8

__global__ __launch_bounds__(256) void gram_dist_kernel(
    const __hip_bfloat16* __restrict__ Abf, const float* __restrict__ norms,
    float* __restrict__ dist, int K) {
  __shared__ short As[TILE][BK + LDSPAD];
  __shared__ short Bs[TILE][BK + LDSPAD];

  int tid = threadIdx.x;
  int wave = tid >> 6, lane = tid & 63;
  int wr = wave >> 1, wc = wave & 1;
  int quad = lane >> 4, l15 = lane & 15;

  int rowBase = blockIdx.y * TILE;
  int colBase = blockIdx.x * TILE;

  float4v acc[4][4];
#pragma unroll
  for (int mi = 0; mi < 4; ++mi)
#pragma unroll
    for (int ni = 0; ni < 4; ++ni) {
      float4v zv = {0.f, 0.f, 0.f, 0.f};
      acc[mi][ni] = zv;
    }

  const short* A16 = (const short*)Abf;

  for (int kc = 0; kc < K; kc += BK) {
#pragma unroll
    for (int g = tid; g < 512; g += 256) {
      int r = g >> 2;
      int c8 = (g & 3) * 8;
      const int4v* srcA =
          (const int4v*)(A16 + (size_t)(rowBase + r) * K + kc + c8);
      *(int4v*)(&As[r][c8]) = *srcA;
      const int4v* srcB =
          (const int4v*)(A16 + (size_t)(colBase + r) * K + kc + c8);
      *(int4v*)(&Bs[r][c8]) = *srcB;
    }
    __syncthreads();

    short8 a[4], b[4];
#pragma unroll
    for (int mi = 0; mi < 4; ++mi)
      a[mi] = *(const short8*)(&As[wr * 64 + mi * 16 + l15][quad * 8]);
#pragma unroll
    for (int ni = 0; ni < 4; ++ni)
      b[ni] = *(const short8*)(&Bs[wc * 64 + ni * 16 + l15][quad * 8]);
#pragma unroll
    for (int mi = 0; mi < 4; ++mi)
#pragma unroll
      for (int ni = 0; ni < 4; ++ni)
        acc[mi][ni] = __builtin_amdgcn_mfma_f32_16x16x32_bf16(
            a[mi], b[ni], acc[mi][ni], 0, 0, 0);
    __syncthreads();
  }

#pragma unroll
  for (int mi = 0; mi < 4; ++mi) {
#pragma unroll
    for (int ni = 0; ni < 4; ++ni) {
      int col = colBase + wc * 64 + ni * 16 + l15;
      float ncol = norms[col];
#pragma unroll
      for (int r = 0; r < 4; ++r) {
        int row = rowBase + wr * 64 + mi * 16 + quad * 4 + r;
        float sq = norms[row] + ncol - 2.0f * acc[mi][ni][r];
        float d = sq > 0.f ? sqrtf(sq) : 0.f;
        if (row == col) d = 0.f;
        dist[(size_t)row * N + col] = d;
      }
    }
  }
}

// ---------------- per-row ranking via LSD radix sort ----------------
// Keys: (q16 << 12) | col, sorted stably on bits 12..27 (4 passes x 4 bits).
// Each thread owns 16 contiguous elements per pass, held in VGPRs.
// LDS addresses XOR-swizzled to kill the stride-64B bank conflict.

#define HPAD 18  // hist row stride (u16), even so rows are u32-aligned

__device__ __forceinline__ int sw4(int i) {
  return i ^ (((i >> 4) ^ (i >> 8)) & 15);
}

__device__ __forceinline__ void radix_sort16(unsigned* bufA, unsigned* bufB,
                                             unsigned short* hist,
                                             unsigned short* sg, int t) {
  const int base = t * 16;
#pragma unroll 1
  for (int pass = 0; pass < 4; ++pass) {
    const int sh = 12 + pass * 4;
    unsigned* in = (pass & 1) ? bufB : bufA;
    unsigned* out = (pass & 1) ? bufA : bufB;

    // ph1: load my 16 elements, count digits via 128-bit one-hot accumulator
    unsigned v[16];
#pragma unroll
    for (int e = 0; e < 16; ++e) v[e] = in[sw4(base + e)];
    unsigned long long acc0 = 0ull, acc1 = 0ull;
#pragma unroll
    for (int e = 0; e < 16; ++e) {
      unsigned d = (v[e] >> sh) & 15u;
      unsigned long long oh = 1ull << ((d & 7u) * 8u);
      if (d < 8u) acc0 += oh; else acc1 += oh;
    }
    // write 16 counts as 8 packed u32 stores into my hist row
    unsigned* hrow32 = (unsigned*)&hist[t * HPAD];
#pragma unroll
    for (int k = 0; k < 8; ++k) {
      unsigned long long src = (k < 4) ? acc0 : acc1;
      unsigned c0 = (unsigned)(src >> (((2 * k) & 7) * 8)) & 255u;
      unsigned c1 = (unsigned)(src >> (((2 * k + 1) & 7) * 8)) & 255u;
      hrow32[k] = c0 | (c1 << 16);
    }
    __syncthreads();

    // ph2 stage A: group partial sums  sg[d][g] = sum over threads in group g
    {
      int d = t & 15, g = t >> 4;
      unsigned s = 0;
#pragma unroll
      for (int i = 0; i < 16; ++i) s += hist[(g * 16 + i) * HPAD + d];
      sg[d * 17 + g] = (unsigned short)s;
    }
    __syncthreads();
    // stage B: per-digit exclusive scan over groups; total in sg[d][16]
    if (t < 16) {
      unsigned run = 0;
#pragma unroll
      for (int g = 0; g < 16; ++g) {
        unsigned c = sg[t * 17 + g];
        sg[t * 17 + g] = (unsigned short)run;
        run += c;
      }
      sg[t * 17 + 16] = (unsigned short)run;
    }
    __syncthreads();
    // stage C: exclusive scan over digit totals
    if (t == 0) {
      unsigned run = 0;
#pragma unroll
      for (int d = 0; d < 16; ++d) {
        unsigned c = sg[d * 17 + 16];
        sg[d * 17 + 16] = (unsigned short)run;
        run += c;
      }
    }
    __syncthreads();
    // stage D: write per-thread exclusive bases back into hist
    {
      int d = t & 15, g = t >> 4;
      unsigned run = (unsigned)sg[d * 17 + 16] + (unsigned)sg[d * 17 + g];
#pragma unroll
      for (int i = 0; i < 16; ++i) {
        int tt = g * 16 + i;
        unsigned c = hist[tt * HPAD + d];
        hist[tt * HPAD + d] = (unsigned short)run;
        run += c;
      }
    }
    __syncthreads();

    // ph3: scatter; within-chunk rank recomputed via running one-hot
    unsigned long long p0 = 0ull, p1 = 0ull;
#pragma unroll
    for (int e = 0; e < 16; ++e) {
      unsigned d = (v[e] >> sh) & 15u;
      unsigned long long psel = (d < 8u) ? p0 : p1;
      unsigned within = (unsigned)(psel >> ((d & 7u) * 8u)) & 255u;
      unsigned pos = (unsigned)hist[t * HPAD + d] + within;
      out[sw4((int)pos)] = v[e];
      unsigned long long oh = 1ull << ((d & 7u) * 8u);
      if (d < 8u) p0 += oh; else p1 += oh;
    }
    __syncthreads();
  }
}

__global__ __launch_bounds__(256) void rank_kernel(
    const float* __restrict__ distx, const float* __restrict__ distz,
    unsigned long long* __restrict__ rank_acc, double* __restrict__ pd_acc) {
  __shared__ unsigned int valA[N];
  __shared__ unsigned int valB[N];
  __shared__ unsigned short rankx[N];
  __shared__ unsigned short hist[256 * HPAD];
  __shared__ unsigned short sg[16 * 17 + 1];

  int row = blockIdx.x;
  int tid = threadIdx.x;
  const float* dxr = distx + (size_t)row * N;
  const float* dzr = distz + (size_t)row * N;

  // build x keys + pairdist partial
  float pd = 0.f;
  for (int j = tid; j < N; j += 256) {
    float dx = dxr[j];
    float dz = dzr[j];
    float df = dz - dx;
    pd += df * df;
    unsigned q = min((unsigned)(dx * 1024.0f), 65535u);  // bound 64
    valA[sw4(j)] = (q << 12) | (unsigned)j;
  }
  __syncthreads();

  radix_sort16(valA, valB, hist, sg, tid);

  for (int p = tid; p < N; p += 256) {
    unsigned v = valA[sw4(p)];
    rankx[v & 4095u] = (unsigned short)p;
  }
  __syncthreads();

  // build z keys
  for (int j = tid; j < N; j += 256) {
    float dz = dzr[j];
    unsigned q = min((unsigned)(dz * 2048.0f), 65535u);  // bound 32
    valA[sw4(j)] = (q << 12) | (unsigned)j;
  }
  __syncthreads();

  radix_sort16(valA, valB, hist, sg, tid);

  int rsum = 0;
  for (int p = tid; p < N; p += 256) {
    unsigned v = valA[sw4(p)];
    int rx = (int)rankx[v & 4095u];
    int d = rx - p;
    rsum += d < 0 ? -d : d;
  }
  __syncthreads();

  // block reduction (alias hist space)
  int* redI = (int*)hist;
  float* redF = (float*)(hist + 1024);
  redI[tid] = rsum;
  redF[tid] = pd;
  __syncthreads();
  for (int s = 128; s > 0; s >>= 1) {
    if (tid < s) {
      redI[tid] += redI[tid + s];
      redF[tid] += redF[tid + s];
    }
    __syncthreads();
  }
  if (tid == 0) {
    atomicAdd(rank_acc, (unsigned long long)redI[0]);
    atomicAdd(pd_acc, (double)redF[0]);
  }
}

// ---------------- finalize ----------------
__global__ void finalize_kernel(const unsigned long long* __restrict__ racc,
                                const double* __restrict__ pacc,
                                float* __restrict__ out) {
  double inv = 1.0 / ((double)N * (double)N);
  double rank_loss = (double)(*racc) * inv / 32.0;  // K = 32
  double pd = (*pacc) * inv;
  out[0] = (float)(rank_loss + 0.5 * pd);
  out[1] = (float)rank_loss;
  out[2] = (float)pd;
}

// ---------------- launch ----------------
extern "C" void kernel_launch(void* const* d_in, const int* in_sizes, int n_in,
                              void* d_out, int out_size, void* d_ws,
                              size_t ws_size, hipStream_t stream) {
  (void)in_sizes; (void)n_in; (void)out_size; (void)ws_size;
  const float* x = (const float*)d_in[0];
  const float* z = (const float*)d_in[1];
  float* out = (float*)d_out;

  char* w = (char*)d_ws;
  float* dist_x = (float*)(w);
  float* dist_z = (float*)(w + 67108864);
  __hip_bfloat16* xb = (__hip_bfloat16*)(w + 134217728);
  __hip_bfloat16* zb = (__hip_bfloat16*)(w + 138412032);
  float* nx = (float*)(w + 138936320);
  float* nz = (float*)(w + 138952704);
  unsigned long long* rank_acc = (unsigned long long*)(w + 138969088);
  double* pd_acc = (double*)(w + 138969096);

  hipMemsetAsync(w + 138969088, 0, 16, stream);

  prep_kernel<<<N, 256, 0, stream>>>(x, z, xb, zb, nx, nz);

  dim3 ggrid(N / TILE, N / TILE);
  gram_dist_kernel<<<ggrid, 256, 0, stream>>>(xb, nx, dist_x, DX);
  gram_dist_kernel<<<ggrid, 256, 0, stream>>>(zb, nz, dist_z, DZ);

  rank_kernel<<<N, 256, 0, stream>>>(dist_x, dist_z, rank_acc, pd_acc);

  finalize_kernel<<<1, 1, 0, stream>>>(rank_acc, pd_acc, out);
}

// Round 3
// 248.821 us; speedup vs baseline: 4.4357x; 1.2948x over previous
//
#include <hip/hip_runtime.h>
#include <hip/hip_bf16.h>

// Problem: N=4096, Dx=512, Dz=64.
// out[0]=total, out[1]=rank_loss, out[2]=pairdist_loss (f32).
//
// Pipeline:
//   1. prep: nx[i]=sum x[i]^2 (f32), nz likewise; cast x,z to bf16.
//   2. gram_dist (bf16 MFMA): d = sqrt(max(n_i + n_j - 2*(A A^T)_ij, 0)),
//      stored as u16 q0 = min(floor(d*qscale), 65535), qscale 1024 (x) /
//      2048 (z). Same quantization as the round-2-validated rank keys.
//   3. rank kernel (counting, no sort): per row, per-row min/max normalize
//      q0 to 13 bits; hist[8192] (u16-packed pairs in u32 words, LDS
//      atomics give stable-ish tie offsets); exclusive scan; rank = base+off.
//      Do x then z in the same block; accumulate sum|rank_x-rank_z| and
//      sum (dz-dx)^2 from dequantized q0.
//   4. finalize: 3 scalars.

#define N 4096
#define DX 512
#define DZ 64
#define NBIN 8192
#define NWRD (NBIN / 2)

typedef __attribute__((ext_vector_type(8))) short short8;
typedef __attribute__((ext_vector_type(4))) float float4v;
typedef __attribute__((ext_vector_type(4))) int int4v;

// ---------------- prep: norms + bf16 casts ----------------
__global__ __launch_bounds__(256) void prep_kernel(
    const float* __restrict__ x, const float* __restrict__ z,
    __hip_bfloat16* __restrict__ xb, __hip_bfloat16* __restrict__ zb,
    float* __restrict__ nx, float* __restrict__ nz) {
  int row = blockIdx.x;
  int tid = threadIdx.x;
  __shared__ float red[256];

  float sx = 0.f;
  for (int c = tid; c < DX; c += 256) {
    float v = x[(size_t)row * DX + c];
    xb[(size_t)row * DX + c] = __float2bfloat16(v);
    sx += v * v;
  }
  red[tid] = sx;
  __syncthreads();
  for (int s = 128; s > 0; s >>= 1) {
    if (tid < s) red[tid] += red[tid + s];
    __syncthreads();
  }
  if (tid == 0) nx[row] = red[0];
  __syncthreads();

  float sz = 0.f;
  if (tid < DZ) {
    float v = z[(size_t)row * DZ + tid];
    zb[(size_t)row * DZ + tid] = __float2bfloat16(v);
    sz = v * v;
  }
  red[tid] = sz;
  __syncthreads();
  for (int s = 128; s > 0; s >>= 1) {
    if (tid < s) red[tid] += red[tid + s];
    __syncthreads();
  }
  if (tid == 0) nz[row] = red[0];
}

// ---------------- bf16 MFMA Gram + quantized-distance epilogue ----------
#define TILE 128
#define BK 32
#define LDSPAD 8

__global__ __launch_bounds__(256) void gram_dist_kernel(
    const __hip_bfloat16* __restrict__ Abf, const float* __restrict__ norms,
    unsigned short* __restrict__ distq, int K, float qscale) {
  __shared__ short As[TILE][BK + LDSPAD];
  __shared__ short Bs[TILE][BK + LDSPAD];

  int tid = threadIdx.x;
  int wave = tid >> 6, lane = tid & 63;
  int wr = wave >> 1, wc = wave & 1;
  int quad = lane >> 4, l15 = lane & 15;

  int rowBase = blockIdx.y * TILE;
  int colBase = blockIdx.x * TILE;

  float4v acc[4][4];
#pragma unroll
  for (int mi = 0; mi < 4; ++mi)
#pragma unroll
    for (int ni = 0; ni < 4; ++ni) {
      float4v zv = {0.f, 0.f, 0.f, 0.f};
      acc[mi][ni] = zv;
    }

  const short* A16 = (const short*)Abf;

  for (int kc = 0; kc < K; kc += BK) {
#pragma unroll
    for (int g = tid; g < 512; g += 256) {
      int r = g >> 2;
      int c8 = (g & 3) * 8;
      const int4v* srcA =
          (const int4v*)(A16 + (size_t)(rowBase + r) * K + kc + c8);
      *(int4v*)(&As[r][c8]) = *srcA;
      const int4v* srcB =
          (const int4v*)(A16 + (size_t)(colBase + r) * K + kc + c8);
      *(int4v*)(&Bs[r][c8]) = *srcB;
    }
    __syncthreads();

    short8 a[4], b[4];
#pragma unroll
    for (int mi = 0; mi < 4; ++mi)
      a[mi] = *(const short8*)(&As[wr * 64 + mi * 16 + l15][quad * 8]);
#pragma unroll
    for (int ni = 0; ni < 4; ++ni)
      b[ni] = *(const short8*)(&Bs[wc * 64 + ni * 16 + l15][quad * 8]);
#pragma unroll
    for (int mi = 0; mi < 4; ++mi)
#pragma unroll
      for (int ni = 0; ni < 4; ++ni)
        acc[mi][ni] = __builtin_amdgcn_mfma_f32_16x16x32_bf16(
            a[mi], b[ni], acc[mi][ni], 0, 0, 0);
    __syncthreads();
  }

#pragma unroll
  for (int mi = 0; mi < 4; ++mi) {
#pragma unroll
    for (int ni = 0; ni < 4; ++ni) {
      int col = colBase + wc * 64 + ni * 16 + l15;
      float ncol = norms[col];
#pragma unroll
      for (int r = 0; r < 4; ++r) {
        int row = rowBase + wr * 64 + mi * 16 + quad * 4 + r;
        float sq = norms[row] + ncol - 2.0f * acc[mi][ni][r];
        float d = sq > 0.f ? sqrtf(sq) : 0.f;
        if (row == col) d = 0.f;
        unsigned q = (unsigned)(d * qscale);
        distq[(size_t)row * N + col] = (unsigned short)(q > 65535u ? 65535u : q);
      }
    }
  }
}

// ---------------- counting-based per-row ranks ----------------
// LDS word-index swizzle: bijective within each 32-word block; makes the
// scan's per-thread-contiguous accesses 2-way (free) instead of 32-way.
__device__ __forceinline__ int hsw(int w) { return w ^ ((w >> 5) & 31); }

// exclusive scan over 8192 u16-packed bins (4096 u32 words), in place.
// thread t owns words [16t,16t+16). counts<=4096 so halves never carry.
__device__ __forceinline__ void scan_hist(unsigned* hist, unsigned* xch,
                                          int t, int lane, int wv) {
  unsigned v[16], pref[16];
  int wb = t * 16;
#pragma unroll
  for (int c = 0; c < 16; ++c) v[c] = hist[hsw(wb + c)];
  unsigned run = 0;
#pragma unroll
  for (int c = 0; c < 16; ++c) {
    unsigned lo = v[c] & 0xFFFFu, hi = v[c] >> 16;
    pref[c] = run | ((run + lo) << 16);
    run += lo + hi;
  }
  unsigned incl = run;
#pragma unroll
  for (int d = 1; d < 64; d <<= 1) {
    unsigned o = (unsigned)__shfl_up((int)incl, d, 64);
    if (lane >= d) incl += o;
  }
  unsigned excl = incl - run;
  if (lane == 63) xch[16 + wv] = incl;
  __syncthreads();
  unsigned base = excl;
#pragma unroll
  for (int w2 = 0; w2 < 4; ++w2)
    if (w2 < wv) base += xch[16 + w2];
#pragma unroll
  for (int c = 0; c < 16; ++c)
    hist[hsw(wb + c)] = pref[c] + base * 0x10001u;
  __syncthreads();
}

__global__ __launch_bounds__(256, 4) void rank_kernel(
    const unsigned short* __restrict__ qx, const unsigned short* __restrict__ qz,
    unsigned long long* __restrict__ rank_acc, double* __restrict__ pd_acc) {
  __shared__ unsigned hist[NWRD];    // 16 KB
  __shared__ unsigned rankx[N / 2];  // 8 KB, u16 pairs
  __shared__ unsigned xch[32];

  int t = threadIdx.x;
  int row = blockIdx.x;
  int lane = t & 63, wv = t >> 6;

  const unsigned short* qxr = qx + (size_t)row * N;
  const unsigned short* qzr = qz + (size_t)row * N;

  uint4 xa = ((const uint4*)qxr)[t * 2], xb2 = ((const uint4*)qxr)[t * 2 + 1];
  uint4 za = ((const uint4*)qzr)[t * 2], zb2 = ((const uint4*)qzr)[t * 2 + 1];
  unsigned xw[8] = {xa.x, xa.y, xa.z, xa.w, xb2.x, xb2.y, xb2.z, xb2.w};
  unsigned zw[8] = {za.x, za.y, za.z, za.w, zb2.x, zb2.y, zb2.z, zb2.w};

  // pairdist partial + per-row off-diagonal min / max (x and z)
  float pd = 0.f;
  unsigned mnx = 65535u, mxx = 0u, mnz = 65535u, mxz = 0u;
  int j0 = t * 16;
#pragma unroll
  for (int c = 0; c < 16; ++c) {
    unsigned qxv = (xw[c >> 1] >> ((c & 1) * 16)) & 0xFFFFu;
    unsigned qzv = (zw[c >> 1] >> ((c & 1) * 16)) & 0xFFFFu;
    // dz-dx = ((qz+.5)/2048 - (qx+.5)/1024) = (qz - 2*qx - 0.5)/2048
    float tt = (float)(int)qzv - 2.0f * (float)(int)qxv - 0.5f;
    pd += tt * tt;
    bool diag = (j0 + c) == row;
    mnx = min(mnx, diag ? 65535u : qxv);
    mnz = min(mnz, diag ? 65535u : qzv);
    mxx = max(mxx, qxv);
    mxz = max(mxz, qzv);
  }
#pragma unroll
  for (int d = 32; d; d >>= 1) {
    mnx = min(mnx, (unsigned)__shfl_xor((int)mnx, d, 64));
    mxx = max(mxx, (unsigned)__shfl_xor((int)mxx, d, 64));
    mnz = min(mnz, (unsigned)__shfl_xor((int)mnz, d, 64));
    mxz = max(mxz, (unsigned)__shfl_xor((int)mxz, d, 64));
  }
  if (lane == 0) {
    xch[wv * 4 + 0] = mnx;
    xch[wv * 4 + 1] = mxx;
    xch[wv * 4 + 2] = mnz;
    xch[wv * 4 + 3] = mxz;
  }
  __syncthreads();
  unsigned fmnx = min(min(xch[0], xch[4]), min(xch[8], xch[12]));
  unsigned fmxx = max(max(xch[1], xch[5]), max(xch[9], xch[13]));
  unsigned fmnz = min(min(xch[2], xch[6]), min(xch[10], xch[14]));
  unsigned fmxz = max(max(xch[3], xch[7]), max(xch[11], xch[15]));

  float lox = (float)(int)fmnx;
  float rgx = (float)(int)(fmxx > fmnx ? fmxx - fmnx : 1u);
  float scx = 8191.0f / rgx;
  float loz = (float)(int)fmnz;
  float rgz = (float)(int)(fmxz > fmnz ? fmxz - fmnz : 1u);
  float scz = 8191.0f / rgz;

  // 13-bit per-row-normalized bins (monotone in q0; diag clamps to 0)
  unsigned q13x[8], q13z[8];
#pragma unroll
  for (int c = 0; c < 16; ++c) {
    unsigned qxv = (xw[c >> 1] >> ((c & 1) * 16)) & 0xFFFFu;
    unsigned qzv = (zw[c >> 1] >> ((c & 1) * 16)) & 0xFFFFu;
    unsigned bx = (unsigned)(int)fminf(
        fmaxf(((float)(int)qxv - lox) * scx, 0.0f), 8191.0f);
    unsigned bz = (unsigned)(int)fminf(
        fmaxf(((float)(int)qzv - loz) * scz, 0.0f), 8191.0f);
    if (c & 1) {
      q13x[c >> 1] |= bx << 16;
      q13z[c >> 1] |= bz << 16;
    } else {
      q13x[c >> 1] = bx;
      q13z[c >> 1] = bz;
    }
  }

  // ---- x phase ----
  for (int w = t; w < NWRD; w += 256) hist[w] = 0u;
  __syncthreads();

  unsigned offx[8];
#pragma unroll
  for (int c = 0; c < 16; ++c) {
    unsigned q = (q13x[c >> 1] >> ((c & 1) * 16)) & 0xFFFFu;
    unsigned sh = (q & 1) * 16;
    unsigned old = atomicAdd(&hist[hsw((int)(q >> 1))], 1u << sh);
    unsigned off = (old >> sh) & 0xFFFFu;
    if (c & 1) offx[c >> 1] |= off << 16; else offx[c >> 1] = off;
  }
  __syncthreads();

  scan_hist(hist, xch, t, lane, wv);

#pragma unroll
  for (int c = 0; c < 16; c += 2) {
    unsigned q0 = q13x[c >> 1] & 0xFFFFu;
    unsigned q1 = q13x[c >> 1] >> 16;
    unsigned b0 = (hist[hsw((int)(q0 >> 1))] >> ((q0 & 1) * 16)) & 0xFFFFu;
    unsigned b1 = (hist[hsw((int)(q1 >> 1))] >> ((q1 & 1) * 16)) & 0xFFFFu;
    unsigned r0 = b0 + (offx[c >> 1] & 0xFFFFu);
    unsigned r1 = b1 + (offx[c >> 1] >> 16);
    rankx[hsw(t * 8 + (c >> 1))] = r0 | (r1 << 16);
  }
  __syncthreads();

  // ---- z phase ----
  for (int w = t; w < NWRD; w += 256) hist[w] = 0u;
  __syncthreads();

  unsigned offz[8];
#pragma unroll
  for (int c = 0; c < 16; ++c) {
    unsigned q = (q13z[c >> 1] >> ((c & 1) * 16)) & 0xFFFFu;
    unsigned sh = (q & 1) * 16;
    unsigned old = atomicAdd(&hist[hsw((int)(q >> 1))], 1u << sh);
    unsigned off = (old >> sh) & 0xFFFFu;
    if (c & 1) offz[c >> 1] |= off << 16; else offz[c >> 1] = off;
  }
  __syncthreads();

  scan_hist(hist, xch, t, lane, wv);

  int rsum = 0;
#pragma unroll
  for (int c = 0; c < 16; c += 2) {
    unsigned q0 = q13z[c >> 1] & 0xFFFFu;
    unsigned q1 = q13z[c >> 1] >> 16;
    unsigned b0 = (hist[hsw((int)(q0 >> 1))] >> ((q0 & 1) * 16)) & 0xFFFFu;
    unsigned b1 = (hist[hsw((int)(q1 >> 1))] >> ((q1 & 1) * 16)) & 0xFFFFu;
    int rz0 = (int)(b0 + (offz[c >> 1] & 0xFFFFu));
    int rz1 = (int)(b1 + (offz[c >> 1] >> 16));
    unsigned rxw = rankx[hsw(t * 8 + (c >> 1))];
    int d0 = rz0 - (int)(rxw & 0xFFFFu);
    int d1 = rz1 - (int)(rxw >> 16);
    rsum += (d0 < 0 ? -d0 : d0) + (d1 < 0 ? -d1 : d1);
  }

  // ---- block reduce + atomics ----
#pragma unroll
  for (int d = 32; d; d >>= 1) {
    rsum += __shfl_xor(rsum, d, 64);
    pd += __shfl_xor(pd, d, 64);
  }
  __syncthreads();
  if (lane == 0) {
    xch[wv] = (unsigned)rsum;
    ((float*)xch)[8 + wv] = pd;
  }
  __syncthreads();
  if (t == 0) {
    unsigned long long rtot = (unsigned long long)xch[0] + xch[1] + xch[2] + xch[3];
    float ptot = ((float*)xch)[8] + ((float*)xch)[9] + ((float*)xch)[10] +
                 ((float*)xch)[11];
    atomicAdd(rank_acc, rtot);
    atomicAdd(pd_acc, (double)ptot);
  }
}

// ---------------- finalize ----------------
__global__ void finalize_kernel(const unsigned long long* __restrict__ racc,
                                const double* __restrict__ pacc,
                                float* __restrict__ out) {
  double inv = 1.0 / ((double)N * (double)N);
  double rank_loss = (double)(*racc) * inv / 32.0;         // K = 32
  double pd = (*pacc) * inv / (2048.0 * 2048.0);           // undo q scaling
  out[0] = (float)(rank_loss + 0.5 * pd);
  out[1] = (float)rank_loss;
  out[2] = (float)pd;
}

// ---------------- launch ----------------
extern "C" void kernel_launch(void* const* d_in, const int* in_sizes, int n_in,
                              void* d_out, int out_size, void* d_ws,
                              size_t ws_size, hipStream_t stream) {
  (void)in_sizes; (void)n_in; (void)out_size; (void)ws_size;
  const float* x = (const float*)d_in[0];
  const float* z = (const float*)d_in[1];
  float* out = (float*)d_out;

  char* w = (char*)d_ws;
  unsigned short* qx16 = (unsigned short*)(w);               // 32 MB
  unsigned short* qz16 = (unsigned short*)(w + 33554432);    // 32 MB
  __hip_bfloat16* xb = (__hip_bfloat16*)(w + 67108864);      // 4 MB
  __hip_bfloat16* zb = (__hip_bfloat16*)(w + 71303168);      // 0.5 MB
  float* nx = (float*)(w + 71827456);                        // 16 KB
  float* nz = (float*)(w + 71843840);                        // 16 KB
  unsigned long long* rank_acc = (unsigned long long*)(w + 71860224);
  double* pd_acc = (double*)(w + 71860232);

  hipMemsetAsync(w + 71860224, 0, 16, stream);

  prep_kernel<<<N, 256, 0, stream>>>(x, z, xb, zb, nx, nz);

  dim3 ggrid(N / TILE, N / TILE);
  gram_dist_kernel<<<ggrid, 256, 0, stream>>>(xb, nx, qx16, DX, 1024.0f);
  gram_dist_kernel<<<ggrid, 256, 0, stream>>>(zb, nz, qz16, DZ, 2048.0f);

  rank_kernel<<<N, 256, 0, stream>>>(qx16, qz16, rank_acc, pd_acc);

  finalize_kernel<<<1, 1, 0, stream>>>(rank_acc, pd_acc, out);
}

// Round 4
// 236.000 us; speedup vs baseline: 4.6767x; 1.0543x over previous
//
#include <hip/hip_runtime.h>
#include <hip/hip_bf16.h>

// Problem: N=4096, Dx=512, Dz=64.
// out[0]=total, out[1]=rank_loss, out[2]=pairdist_loss (f32).
//
// Pipeline:
//   1. prep: nx[i]=sum x[i]^2 (f32), nz likewise; cast x,z to bf16.
//   2. gram_dist (bf16 MFMA, global_load_lds 16B staging):
//      d = sqrt(max(n_i + n_j - 2*(A A^T)_ij, 0)), stored u16
//      q0 = min(floor(d*qscale), 65535), qscale 1024 (x) / 2048 (z).
//   3. rank kernel (counting): per row normalize q0 to 13-bit bins;
//      count pass (ds_add no-return) -> exclusive scan -> assign pass
//      (ds_add_rtn on scanned hist, old value IS the rank). No per-thread
//      offset arrays -> no scratch spill (round-3 bug: 148 MB spill traffic).
//   4. finalize: 3 scalars.

#define N 4096
#define DX 512
#define DZ 64
#define NBIN 8192
#define NWRD (NBIN / 2)

typedef __attribute__((ext_vector_type(8))) short short8;
typedef __attribute__((ext_vector_type(4))) float float4v;

// ---------------- async 16B global -> LDS ----------------
__device__ __forceinline__ void async16(const void* g, void* l) {
  __builtin_amdgcn_global_load_lds(
      (const __attribute__((address_space(1))) unsigned int*)(g),
      (__attribute__((address_space(3))) unsigned int*)(l), 16, 0, 0);
}

// ---------------- prep: norms + bf16 casts ----------------
__global__ __launch_bounds__(256) void prep_kernel(
    const float* __restrict__ x, const float* __restrict__ z,
    __hip_bfloat16* __restrict__ xb, __hip_bfloat16* __restrict__ zb,
    float* __restrict__ nx, float* __restrict__ nz) {
  int row = blockIdx.x;
  int tid = threadIdx.x;
  __shared__ float red[256];

  float sx = 0.f;
  for (int c = tid; c < DX; c += 256) {
    float v = x[(size_t)row * DX + c];
    xb[(size_t)row * DX + c] = __float2bfloat16(v);
    sx += v * v;
  }
  red[tid] = sx;
  __syncthreads();
  for (int s = 128; s > 0; s >>= 1) {
    if (tid < s) red[tid] += red[tid + s];
    __syncthreads();
  }
  if (tid == 0) nx[row] = red[0];
  __syncthreads();

  float sz = 0.f;
  if (tid < DZ) {
    float v = z[(size_t)row * DZ + tid];
    zb[(size_t)row * DZ + tid] = __float2bfloat16(v);
    sz = v * v;
  }
  red[tid] = sz;
  __syncthreads();
  for (int s = 128; s > 0; s >>= 1) {
    if (tid < s) red[tid] += red[tid + s];
    __syncthreads();
  }
  if (tid == 0) nz[row] = red[0];
}

// ---------------- bf16 MFMA Gram + quantized-distance epilogue ----------
// 128x128 tile, BK=32, unpadded contiguous LDS tiles staged via
// global_load_lds width=16 (LDS layout == wave-uniform base + lane*16).
#define TILE 128
#define BK 32

__global__ __launch_bounds__(256) void gram_dist_kernel(
    const __hip_bfloat16* __restrict__ Abf, const float* __restrict__ norms,
    unsigned short* __restrict__ distq, int K, float qscale) {
  __shared__ short As[TILE * BK];  // 8 KB, row-major [128][32]
  __shared__ short Bs[TILE * BK];

  int tid = threadIdx.x;
  int wave = tid >> 6, lane = tid & 63;
  int wr = wave >> 1, wc = wave & 1;
  int quad = lane >> 4, l15 = lane & 15;

  int rowBase = blockIdx.y * TILE;
  int colBase = blockIdx.x * TILE;

  float4v acc[4][4];
#pragma unroll
  for (int mi = 0; mi < 4; ++mi)
#pragma unroll
    for (int ni = 0; ni < 4; ++ni) {
      float4v zv = {0.f, 0.f, 0.f, 0.f};
      acc[mi][ni] = zv;
    }

  const char* Ab = (const char*)Abf;
  const size_t rb = (size_t)K * 2;  // row bytes
  int chunk0 = wave * 2, chunk1 = wave * 2 + 1;
  int rl = lane >> 2;        // row within a 16-row chunk (4 lanes/row)
  int cl = (lane & 3) * 16;  // byte col within 64B row

  for (int kc = 0; kc < K; kc += BK) {
    const char* base = Ab + (size_t)kc * 2 + cl;
    async16(base + (size_t)(rowBase + chunk0 * 16 + rl) * rb,
            &As[chunk0 * 512]);
    async16(base + (size_t)(rowBase + chunk1 * 16 + rl) * rb,
            &As[chunk1 * 512]);
    async16(base + (size_t)(colBase + chunk0 * 16 + rl) * rb,
            &Bs[chunk0 * 512]);
    async16(base + (size_t)(colBase + chunk1 * 16 + rl) * rb,
            &Bs[chunk1 * 512]);
    __syncthreads();  // drains vmcnt (global_load_lds) per barrier semantics

    short8 a[4], b[4];
#pragma unroll
    for (int mi = 0; mi < 4; ++mi)
      a[mi] = *(const short8*)(&As[(wr * 64 + mi * 16 + l15) * BK + quad * 8]);
#pragma unroll
    for (int ni = 0; ni < 4; ++ni)
      b[ni] = *(const short8*)(&Bs[(wc * 64 + ni * 16 + l15) * BK + quad * 8]);
#pragma unroll
    for (int mi = 0; mi < 4; ++mi)
#pragma unroll
      for (int ni = 0; ni < 4; ++ni)
        acc[mi][ni] = __builtin_amdgcn_mfma_f32_16x16x32_bf16(
            a[mi], b[ni], acc[mi][ni], 0, 0, 0);
    __syncthreads();
  }

#pragma unroll
  for (int mi = 0; mi < 4; ++mi) {
#pragma unroll
    for (int ni = 0; ni < 4; ++ni) {
      int col = colBase + wc * 64 + ni * 16 + l15;
      float ncol = norms[col];
#pragma unroll
      for (int r = 0; r < 4; ++r) {
        int row = rowBase + wr * 64 + mi * 16 + quad * 4 + r;
        float sq = norms[row] + ncol - 2.0f * acc[mi][ni][r];
        float d = sq > 0.f ? sqrtf(sq) : 0.f;
        if (row == col) d = 0.f;
        unsigned q = (unsigned)(d * qscale);
        distq[(size_t)row * N + col] =
            (unsigned short)(q > 65535u ? 65535u : q);
      }
    }
  }
}

// ---------------- counting-based per-row ranks ----------------
// Word-index swizzle (bijective per 32-word block): sequential per-thread
// patterns become 2-way bank aliasing (free) instead of 32-way.
__device__ __forceinline__ int hsw(int w) { return w ^ ((w >> 5) & 31); }

// Streaming in-place exclusive scan over 8192 u16-packed bins (4096 words).
// Thread t owns words [16t,16t+16). ~3 live registers; no arrays.
__device__ __forceinline__ void scan_hist(unsigned* hist, unsigned* xch,
                                          int t, int lane, int wv) {
  unsigned run = 0;
  int wb = t * 16;
#pragma unroll
  for (int c = 0; c < 16; ++c) {
    int w = hsw(wb + c);
    unsigned v = hist[w];
    unsigned lo = v & 0xFFFFu;
    hist[w] = run | ((run + lo) << 16);
    run += lo + (v >> 16);
  }
  unsigned incl = run;
#pragma unroll
  for (int d = 1; d < 64; d <<= 1) {
    unsigned o = (unsigned)__shfl_up((int)incl, d, 64);
    if (lane >= d) incl += o;
  }
  unsigned excl = incl - run;
  if (lane == 63) xch[16 + wv] = incl;
  __syncthreads();
  unsigned base = excl;
#pragma unroll
  for (int w2 = 0; w2 < 4; ++w2)
    if (w2 < wv) base += xch[16 + w2];
  unsigned add = base * 0x10001u;
#pragma unroll
  for (int c = 0; c < 16; ++c) hist[hsw(wb + c)] += add;
  __syncthreads();
}

__global__ __launch_bounds__(256) void rank_kernel(
    const unsigned short* __restrict__ qx,
    const unsigned short* __restrict__ qz,
    unsigned long long* __restrict__ rank_acc, double* __restrict__ pd_acc) {
  __shared__ unsigned hist[NWRD];    // 16 KB
  __shared__ unsigned rankx[N / 2];  // 8 KB, u16 pairs
  __shared__ unsigned xch[32];

  int t = threadIdx.x, row = blockIdx.x;
  int lane = t & 63, wv = t >> 6;
  const uint4* px = (const uint4*)(qx + (size_t)row * N);
  const uint4* pz = (const uint4*)(qz + (size_t)row * N);

  // ---- pass 0: pairdist partial + per-row min/max (streaming) ----
  float pd = 0.f;
  unsigned mnx = 65535u, mxx = 0u, mnz = 65535u, mxz = 0u;
#pragma unroll
  for (int h = 0; h < 2; ++h) {
    uint4 xv = px[t * 2 + h];
    uint4 zv = pz[t * 2 + h];
    unsigned xw[4] = {xv.x, xv.y, xv.z, xv.w};
    unsigned zw[4] = {zv.x, zv.y, zv.z, zv.w};
#pragma unroll
    for (int c = 0; c < 8; ++c) {
      unsigned qxv = (xw[c >> 1] >> ((c & 1) * 16)) & 0xFFFFu;
      unsigned qzv = (zw[c >> 1] >> ((c & 1) * 16)) & 0xFFFFu;
      // dz-dx = ((qz+.5)/2048 - (qx+.5)/1024) = (qz - 2*qx - 0.5)/2048
      float tt = (float)(int)qzv - 2.0f * (float)(int)qxv - 0.5f;
      pd += tt * tt;
      bool diag = (t * 16 + h * 8 + c) == row;
      mnx = min(mnx, diag ? 65535u : qxv);
      mnz = min(mnz, diag ? 65535u : qzv);
      mxx = max(mxx, qxv);
      mxz = max(mxz, qzv);
    }
  }
#pragma unroll
  for (int d = 32; d; d >>= 1) {
    mnx = min(mnx, (unsigned)__shfl_xor((int)mnx, d, 64));
    mxx = max(mxx, (unsigned)__shfl_xor((int)mxx, d, 64));
    mnz = min(mnz, (unsigned)__shfl_xor((int)mnz, d, 64));
    mxz = max(mxz, (unsigned)__shfl_xor((int)mxz, d, 64));
  }
  if (lane == 0) {
    xch[wv * 4 + 0] = mnx;
    xch[wv * 4 + 1] = mxx;
    xch[wv * 4 + 2] = mnz;
    xch[wv * 4 + 3] = mxz;
  }
  __syncthreads();
  unsigned fmnx = min(min(xch[0], xch[4]), min(xch[8], xch[12]));
  unsigned fmxx = max(max(xch[1], xch[5]), max(xch[9], xch[13]));
  unsigned fmnz = min(min(xch[2], xch[6]), min(xch[10], xch[14]));
  unsigned fmxz = max(max(xch[3], xch[7]), max(xch[11], xch[15]));

  float lox = (float)(int)fmnx;
  float scx = 8191.0f / (float)(int)(fmxx > fmnx ? fmxx - fmnx : 1u);
  float loz = (float)(int)fmnz;
  float scz = 8191.0f / (float)(int)(fmxz > fmnz ? fmxz - fmnz : 1u);

  int rsum = 0;
  int wb2 = t * 8;

  // ================= x phase, then z phase =================
#pragma unroll 1
  for (int phase = 0; phase < 2; ++phase) {
    const uint4* p = phase ? pz : px;
    float lo = phase ? loz : lox;
    float sc = phase ? scz : scx;

    // zero hist
    for (int w = t; w < NWRD; w += 256) hist[w] = 0u;

    // load my 16 elements, compute packed 13-bit bins (8 live regs)
    uint4 a0 = p[t * 2], a1 = p[t * 2 + 1];
    unsigned rw[8] = {a0.x, a0.y, a0.z, a0.w, a1.x, a1.y, a1.z, a1.w};
    unsigned q13[8];
#pragma unroll
    for (int c = 0; c < 16; ++c) {
      unsigned qv = (rw[c >> 1] >> ((c & 1) * 16)) & 0xFFFFu;
      unsigned b = (unsigned)(int)fminf(
          fmaxf(((float)(int)qv - lo) * sc, 0.0f), 8191.0f);
      if (c & 1) q13[c >> 1] |= b << 16; else q13[c >> 1] = b;
    }
    __syncthreads();  // hist zeroed by all

    // count pass (non-returning LDS atomics)
#pragma unroll
    for (int c = 0; c < 16; ++c) {
      unsigned q = (q13[c >> 1] >> ((c & 1) * 16)) & 0xFFFFu;
      atomicAdd(&hist[hsw((int)(q >> 1))], 1u << ((q & 1) * 16));
    }
    __syncthreads();

    scan_hist(hist, xch, t, lane, wv);

    // assign pass: old value of scanned-hist atomic IS the rank
#pragma unroll
    for (int c = 0; c < 16; c += 2) {
      unsigned q0 = q13[c >> 1] & 0xFFFFu, q1 = q13[c >> 1] >> 16;
      unsigned sh0 = (q0 & 1) * 16, sh1 = (q1 & 1) * 16;
      unsigned o0 = atomicAdd(&hist[hsw((int)(q0 >> 1))], 1u << sh0);
      unsigned o1 = atomicAdd(&hist[hsw((int)(q1 >> 1))], 1u << sh1);
      unsigned r0 = (o0 >> sh0) & 0xFFFFu, r1 = (o1 >> sh1) & 0xFFFFu;
      if (phase == 0) {
        rankx[hsw(wb2 + (c >> 1))] = r0 | (r1 << 16);
      } else {
        unsigned rxw = rankx[hsw(wb2 + (c >> 1))];
        int d0 = (int)r0 - (int)(rxw & 0xFFFFu);
        int d1 = (int)r1 - (int)(rxw >> 16);
        rsum += (d0 < 0 ? -d0 : d0) + (d1 < 0 ? -d1 : d1);
      }
    }
    __syncthreads();
  }

  // ---- block reduce + global atomics ----
#pragma unroll
  for (int d = 32; d; d >>= 1) {
    rsum += __shfl_xor(rsum, d, 64);
    pd += __shfl_xor(pd, d, 64);
  }
  if (lane == 0) {
    xch[wv] = (unsigned)rsum;
    ((float*)xch)[8 + wv] = pd;
  }
  __syncthreads();
  if (t == 0) {
    unsigned long long rtot =
        (unsigned long long)xch[0] + xch[1] + xch[2] + xch[3];
    float ptot = ((float*)xch)[8] + ((float*)xch)[9] + ((float*)xch)[10] +
                 ((float*)xch)[11];
    atomicAdd(rank_acc, rtot);
    atomicAdd(pd_acc, (double)ptot);
  }
}

// ---------------- finalize ----------------
__global__ void finalize_kernel(const unsigned long long* __restrict__ racc,
                                const double* __restrict__ pacc,
                                float* __restrict__ out) {
  double inv = 1.0 / ((double)N * (double)N);
  double rank_loss = (double)(*racc) * inv / 32.0;  // K = 32
  double pd = (*pacc) * inv / (2048.0 * 2048.0);    // undo q scaling
  out[0] = (float)(rank_loss + 0.5 * pd);
  out[1] = (float)rank_loss;
  out[2] = (float)pd;
}

// ---------------- launch ----------------
extern "C" void kernel_launch(void* const* d_in, const int* in_sizes, int n_in,
                              void* d_out, int out_size, void* d_ws,
                              size_t ws_size, hipStream_t stream) {
  (void)in_sizes; (void)n_in; (void)out_size; (void)ws_size;
  const float* x = (const float*)d_in[0];
  const float* z = (const float*)d_in[1];
  float* out = (float*)d_out;

  char* w = (char*)d_ws;
  unsigned short* qx16 = (unsigned short*)(w);             // 32 MB
  unsigned short* qz16 = (unsigned short*)(w + 33554432);  // 32 MB
  __hip_bfloat16* xb = (__hip_bfloat16*)(w + 67108864);    // 4 MB
  __hip_bfloat16* zb = (__hip_bfloat16*)(w + 71303168);    // 0.5 MB
  float* nx = (float*)(w + 71827456);
  float* nz = (float*)(w + 71843840);
  unsigned long long* rank_acc = (unsigned long long*)(w + 71860224);
  double* pd_acc = (double*)(w + 71860232);

  hipMemsetAsync(w + 71860224, 0, 16, stream);

  prep_kernel<<<N, 256, 0, stream>>>(x, z, xb, zb, nx, nz);

  dim3 ggrid(N / TILE, N / TILE);
  gram_dist_kernel<<<ggrid, 256, 0, stream>>>(xb, nx, qx16, DX, 1024.0f);
  gram_dist_kernel<<<ggrid, 256, 0, stream>>>(zb, nz, qz16, DZ, 2048.0f);

  rank_kernel<<<N, 256, 0, stream>>>(qx16, qz16, rank_acc, pd_acc);

  finalize_kernel<<<1, 1, 0, stream>>>(rank_acc, pd_acc, out);
}

// Round 5
// 233.099 us; speedup vs baseline: 4.7349x; 1.0124x over previous
//
#include <hip/hip_runtime.h>
#include <hip/hip_bf16.h>

// Problem: N=4096, Dx=512, Dz=64.
// out[0]=total, out[1]=rank_loss, out[2]=pairdist_loss (f32).
//
// Pipeline:
//   1. prep: nx[i]=sum x[i]^2 (f32), nz likewise; cast x,z to bf16.
//   2. gram_dist (bf16 MFMA, global_load_lds 16B staging):
//      d = sqrt(max(n_i + n_j - 2*(A A^T)_ij, 0)), stored u16
//      q0 = min(floor(d*qscale), 65535), qscale 1024 (x) / 2048 (z).
//   3. rank kernel (counting, fused x+z): per row normalize q0 to 12-bit
//      bins; DUAL histograms (x and z) counted in one pass, scanned in
//      parallel (waves 0-1 scan histX, waves 2-3 histZ), then one assign
//      pass produces rank_x and rank_z together -> |rx-rz| inline. No rankx
//      array, ~6 barriers/row, ~128 LDS ops/thread (round-4: ~12 / ~240).
//   4. finalize: 3 scalars.

#define N 4096
#define DX 512
#define DZ 64
#define NBIN 4096          // 12-bit normalized bins
#define NWRD (NBIN / 2)    // u16-packed pairs -> 2048 u32 words per hist

typedef __attribute__((ext_vector_type(8))) short short8;
typedef __attribute__((ext_vector_type(4))) float float4v;

// ---------------- async 16B global -> LDS ----------------
__device__ __forceinline__ void async16(const void* g, void* l) {
  __builtin_amdgcn_global_load_lds(
      (const __attribute__((address_space(1))) unsigned int*)(g),
      (__attribute__((address_space(3))) unsigned int*)(l), 16, 0, 0);
}

// ---------------- prep: norms + bf16 casts ----------------
__global__ __launch_bounds__(256) void prep_kernel(
    const float* __restrict__ x, const float* __restrict__ z,
    __hip_bfloat16* __restrict__ xb, __hip_bfloat16* __restrict__ zb,
    float* __restrict__ nx, float* __restrict__ nz) {
  int row = blockIdx.x;
  int tid = threadIdx.x;
  __shared__ float red[256];

  float sx = 0.f;
  for (int c = tid; c < DX; c += 256) {
    float v = x[(size_t)row * DX + c];
    xb[(size_t)row * DX + c] = __float2bfloat16(v);
    sx += v * v;
  }
  red[tid] = sx;
  __syncthreads();
  for (int s = 128; s > 0; s >>= 1) {
    if (tid < s) red[tid] += red[tid + s];
    __syncthreads();
  }
  if (tid == 0) nx[row] = red[0];
  __syncthreads();

  float sz = 0.f;
  if (tid < DZ) {
    float v = z[(size_t)row * DZ + tid];
    zb[(size_t)row * DZ + tid] = __float2bfloat16(v);
    sz = v * v;
  }
  red[tid] = sz;
  __syncthreads();
  for (int s = 128; s > 0; s >>= 1) {
    if (tid < s) red[tid] += red[tid + s];
    __syncthreads();
  }
  if (tid == 0) nz[row] = red[0];
}

// ---------------- bf16 MFMA Gram + quantized-distance epilogue ----------
#define TILE 128
#define BK 32

__global__ __launch_bounds__(256) void gram_dist_kernel(
    const __hip_bfloat16* __restrict__ Abf, const float* __restrict__ norms,
    unsigned short* __restrict__ distq, int K, float qscale) {
  __shared__ short As[TILE * BK];  // 8 KB, row-major [128][32]
  __shared__ short Bs[TILE * BK];

  int tid = threadIdx.x;
  int wave = tid >> 6, lane = tid & 63;
  int wr = wave >> 1, wc = wave & 1;
  int quad = lane >> 4, l15 = lane & 15;

  int rowBase = blockIdx.y * TILE;
  int colBase = blockIdx.x * TILE;

  float4v acc[4][4];
#pragma unroll
  for (int mi = 0; mi < 4; ++mi)
#pragma unroll
    for (int ni = 0; ni < 4; ++ni) {
      float4v zv = {0.f, 0.f, 0.f, 0.f};
      acc[mi][ni] = zv;
    }

  const char* Ab = (const char*)Abf;
  const size_t rb = (size_t)K * 2;  // row bytes
  int chunk0 = wave * 2, chunk1 = wave * 2 + 1;
  int rl = lane >> 2;        // row within a 16-row chunk (4 lanes/row)
  int cl = (lane & 3) * 16;  // byte col within 64B row

  for (int kc = 0; kc < K; kc += BK) {
    const char* base = Ab + (size_t)kc * 2 + cl;
    async16(base + (size_t)(rowBase + chunk0 * 16 + rl) * rb,
            &As[chunk0 * 512]);
    async16(base + (size_t)(rowBase + chunk1 * 16 + rl) * rb,
            &As[chunk1 * 512]);
    async16(base + (size_t)(colBase + chunk0 * 16 + rl) * rb,
            &Bs[chunk0 * 512]);
    async16(base + (size_t)(colBase + chunk1 * 16 + rl) * rb,
            &Bs[chunk1 * 512]);
    __syncthreads();

    short8 a[4], b[4];
#pragma unroll
    for (int mi = 0; mi < 4; ++mi)
      a[mi] = *(const short8*)(&As[(wr * 64 + mi * 16 + l15) * BK + quad * 8]);
#pragma unroll
    for (int ni = 0; ni < 4; ++ni)
      b[ni] = *(const short8*)(&Bs[(wc * 64 + ni * 16 + l15) * BK + quad * 8]);
#pragma unroll
    for (int mi = 0; mi < 4; ++mi)
#pragma unroll
      for (int ni = 0; ni < 4; ++ni)
        acc[mi][ni] = __builtin_amdgcn_mfma_f32_16x16x32_bf16(
            a[mi], b[ni], acc[mi][ni], 0, 0, 0);
    __syncthreads();
  }

#pragma unroll
  for (int mi = 0; mi < 4; ++mi) {
#pragma unroll
    for (int ni = 0; ni < 4; ++ni) {
      int col = colBase + wc * 64 + ni * 16 + l15;
      float ncol = norms[col];
#pragma unroll
      for (int r = 0; r < 4; ++r) {
        int row = rowBase + wr * 64 + mi * 16 + quad * 4 + r;
        float sq = norms[row] + ncol - 2.0f * acc[mi][ni][r];
        float d = sq > 0.f ? sqrtf(sq) : 0.f;
        if (row == col) d = 0.f;
        unsigned q = (unsigned)(d * qscale);
        distq[(size_t)row * N + col] =
            (unsigned short)(q > 65535u ? 65535u : q);
      }
    }
  }
}

// ---------------- fused counting-based per-row ranks ----------------
// Word-index swizzle (bijective per 32-word block): sequential per-thread
// scan accesses become 2-way bank aliasing (free) instead of 32-way.
__device__ __forceinline__ int hsw(int w) { return w ^ ((w >> 5) & 31); }

__global__ __launch_bounds__(256) void rank_kernel(
    const unsigned short* __restrict__ qx,
    const unsigned short* __restrict__ qz,
    unsigned long long* __restrict__ rank_acc, double* __restrict__ pd_acc) {
  __shared__ unsigned histX[NWRD];  // 8 KB
  __shared__ unsigned histZ[NWRD];  // 8 KB
  __shared__ unsigned xch[32];

  int t = threadIdx.x, row = blockIdx.x;
  int lane = t & 63, wv = t >> 6;
  const uint4* px = (const uint4*)(qx + (size_t)row * N);
  const uint4* pz = (const uint4*)(qz + (size_t)row * N);

  // ---- load my 16 x and 16 z values; keep resident (16 VGPRs) ----
  uint4 xa = px[t * 2], xb4 = px[t * 2 + 1];
  uint4 za = pz[t * 2], zb4 = pz[t * 2 + 1];
  unsigned xw[8] = {xa.x, xa.y, xa.z, xa.w, xb4.x, xb4.y, xb4.z, xb4.w};
  unsigned zw[8] = {za.x, za.y, za.z, za.w, zb4.x, zb4.y, zb4.z, zb4.w};

  // zero both hists while loads are in flight (no dependency)
#pragma unroll
  for (int i = 0; i < 8; ++i) {
    histX[t + 256 * i] = 0u;
    histZ[t + 256 * i] = 0u;
  }

  // ---- pairdist partial + per-row off-diagonal min / max ----
  float pd = 0.f;
  unsigned mnx = 65535u, mxx = 0u, mnz = 65535u, mxz = 0u;
#pragma unroll
  for (int c = 0; c < 16; ++c) {
    unsigned qxv = (xw[c >> 1] >> ((c & 1) * 16)) & 0xFFFFu;
    unsigned qzv = (zw[c >> 1] >> ((c & 1) * 16)) & 0xFFFFu;
    // dz-dx = ((qz+.5)/2048 - (qx+.5)/1024) = (qz - 2*qx - 0.5)/2048
    float tt = (float)(int)qzv - 2.0f * (float)(int)qxv - 0.5f;
    pd += tt * tt;
    bool diag = (t * 16 + c) == row;
    mnx = min(mnx, diag ? 65535u : qxv);
    mnz = min(mnz, diag ? 65535u : qzv);
    mxx = max(mxx, qxv);
    mxz = max(mxz, qzv);
  }
#pragma unroll
  for (int d = 32; d; d >>= 1) {
    mnx = min(mnx, (unsigned)__shfl_xor((int)mnx, d, 64));
    mxx = max(mxx, (unsigned)__shfl_xor((int)mxx, d, 64));
    mnz = min(mnz, (unsigned)__shfl_xor((int)mnz, d, 64));
    mxz = max(mxz, (unsigned)__shfl_xor((int)mxz, d, 64));
  }
  if (lane == 0) {
    xch[wv * 4 + 0] = mnx;
    xch[wv * 4 + 1] = mxx;
    xch[wv * 4 + 2] = mnz;
    xch[wv * 4 + 3] = mxz;
  }
  __syncthreads();  // covers hist zeroing + minmax exchange
  unsigned fmnx = min(min(xch[0], xch[4]), min(xch[8], xch[12]));
  unsigned fmxx = max(max(xch[1], xch[5]), max(xch[9], xch[13]));
  unsigned fmnz = min(min(xch[2], xch[6]), min(xch[10], xch[14]));
  unsigned fmxz = max(max(xch[3], xch[7]), max(xch[11], xch[15]));

  float lox = (float)(int)fmnx;
  float scx = (float)(NBIN - 1) / (float)(int)(fmxx > fmnx ? fmxx - fmnx : 1u);
  float loz = (float)(int)fmnz;
  float scz = (float)(NBIN - 1) / (float)(int)(fmxz > fmnz ? fmxz - fmnz : 1u);

  // ---- count pass: 32 independent non-returning LDS atomics ----
#pragma unroll
  for (int c = 0; c < 16; ++c) {
    unsigned qxv = (xw[c >> 1] >> ((c & 1) * 16)) & 0xFFFFu;
    unsigned qzv = (zw[c >> 1] >> ((c & 1) * 16)) & 0xFFFFu;
    unsigned bx = (unsigned)(int)fminf(
        fmaxf(((float)(int)qxv - lox) * scx, 0.0f), (float)(NBIN - 1));
    unsigned bz = (unsigned)(int)fminf(
        fmaxf(((float)(int)qzv - loz) * scz, 0.0f), (float)(NBIN - 1));
    atomicAdd(&histX[hsw((int)(bx >> 1))], 1u << ((bx & 1) * 16));
    atomicAdd(&histZ[hsw((int)(bz >> 1))], 1u << ((bz & 1) * 16));
  }
  __syncthreads();

  // ---- dual exclusive scan: waves 0-1 -> histX, waves 2-3 -> histZ ----
  {
    unsigned* h = (t < 128) ? histX : histZ;
    int tt = t & 127;
    int wb = tt * 16;
    unsigned run = 0;
#pragma unroll
    for (int c = 0; c < 16; ++c) {
      int w = hsw(wb + c);
      unsigned v = h[w];
      unsigned lo = v & 0xFFFFu;
      h[w] = run | ((run + lo) << 16);
      run += lo + (v >> 16);
    }
    unsigned incl = run;
#pragma unroll
    for (int d = 1; d < 64; d <<= 1) {
      unsigned o = (unsigned)__shfl_up((int)incl, d, 64);
      if (lane >= d) incl += o;
    }
    if (lane == 63) xch[16 + wv] = incl;
    __syncthreads();
    unsigned base = incl - run;  // exclusive within my wave
    if (wv & 1) base += xch[16 + (wv - 1)];  // add lower wave of my hist
    unsigned add = base * 0x10001u;
#pragma unroll
    for (int c = 0; c < 16; ++c) h[hsw(wb + c)] += add;
  }
  __syncthreads();

  // ---- assign pass: rank_x and rank_z together, |rx-rz| inline ----
  int rsum = 0;
#pragma unroll
  for (int c = 0; c < 16; ++c) {
    unsigned qxv = (xw[c >> 1] >> ((c & 1) * 16)) & 0xFFFFu;
    unsigned qzv = (zw[c >> 1] >> ((c & 1) * 16)) & 0xFFFFu;
    unsigned bx = (unsigned)(int)fminf(
        fmaxf(((float)(int)qxv - lox) * scx, 0.0f), (float)(NBIN - 1));
    unsigned bz = (unsigned)(int)fminf(
        fmaxf(((float)(int)qzv - loz) * scz, 0.0f), (float)(NBIN - 1));
    unsigned shx = (bx & 1) * 16, shz = (bz & 1) * 16;
    unsigned ox = atomicAdd(&histX[hsw((int)(bx >> 1))], 1u << shx);
    unsigned oz = atomicAdd(&histZ[hsw((int)(bz >> 1))], 1u << shz);
    int rx = (int)((ox >> shx) & 0xFFFFu);
    int rz = (int)((oz >> shz) & 0xFFFFu);
    int d = rx - rz;
    rsum += d < 0 ? -d : d;
  }

  // ---- block reduce + global atomics ----
#pragma unroll
  for (int d = 32; d; d >>= 1) {
    rsum += __shfl_xor(rsum, d, 64);
    pd += __shfl_xor(pd, d, 64);
  }
  __syncthreads();
  if (lane == 0) {
    xch[wv] = (unsigned)rsum;
    ((float*)xch)[8 + wv] = pd;
  }
  __syncthreads();
  if (t == 0) {
    unsigned long long rtot =
        (unsigned long long)xch[0] + xch[1] + xch[2] + xch[3];
    float ptot = ((float*)xch)[8] + ((float*)xch)[9] + ((float*)xch)[10] +
                 ((float*)xch)[11];
    atomicAdd(rank_acc, rtot);
    atomicAdd(pd_acc, (double)ptot);
  }
}

// ---------------- finalize ----------------
__global__ void finalize_kernel(const unsigned long long* __restrict__ racc,
                                const double* __restrict__ pacc,
                                float* __restrict__ out) {
  double inv = 1.0 / ((double)N * (double)N);
  double rank_loss = (double)(*racc) * inv / 32.0;  // K = 32
  double pd = (*pacc) * inv / (2048.0 * 2048.0);    // undo q scaling
  out[0] = (float)(rank_loss + 0.5 * pd);
  out[1] = (float)rank_loss;
  out[2] = (float)pd;
}

// ---------------- launch ----------------
extern "C" void kernel_launch(void* const* d_in, const int* in_sizes, int n_in,
                              void* d_out, int out_size, void* d_ws,
                              size_t ws_size, hipStream_t stream) {
  (void)in_sizes; (void)n_in; (void)out_size; (void)ws_size;
  const float* x = (const float*)d_in[0];
  const float* z = (const float*)d_in[1];
  float* out = (float*)d_out;

  char* w = (char*)d_ws;
  unsigned short* qx16 = (unsigned short*)(w);             // 32 MB
  unsigned short* qz16 = (unsigned short*)(w + 33554432);  // 32 MB
  __hip_bfloat16* xb = (__hip_bfloat16*)(w + 67108864);    // 4 MB
  __hip_bfloat16* zb = (__hip_bfloat16*)(w + 71303168);    // 0.5 MB
  float* nx = (float*)(w + 71827456);
  float* nz = (float*)(w + 71843840);
  unsigned long long* rank_acc = (unsigned long long*)(w + 71860224);
  double* pd_acc = (double*)(w + 71860232);

  hipMemsetAsync(w + 71860224, 0, 16, stream);

  prep_kernel<<<N, 256, 0, stream>>>(x, z, xb, zb, nx, nz);

  dim3 ggrid(N / TILE, N / TILE);
  gram_dist_kernel<<<ggrid, 256, 0, stream>>>(xb, nx, qx16, DX, 1024.0f);
  gram_dist_kernel<<<ggrid, 256, 0, stream>>>(zb, nz, qz16, DZ, 2048.0f);

  rank_kernel<<<N, 256, 0, stream>>>(qx16, qz16, rank_acc, pd_acc);

  finalize_kernel<<<1, 1, 0, stream>>>(rank_acc, pd_acc, out);
}

// Round 6
// 230.210 us; speedup vs baseline: 4.7943x; 1.0125x over previous
//
#include <hip/hip_runtime.h>
#include <hip/hip_bf16.h>

// Problem: N=4096, Dx=512, Dz=64.
// out[0]=total, out[1]=rank_loss, out[2]=pairdist_loss (f32).
//
// Pipeline:
//   1. prep: nx[i]=sum x[i]^2 (f32), nz likewise; cast x,z to bf16.
//   2. gram_dist (bf16 MFMA, global_load_lds 16B staging):
//      d = sqrt(max(n_i + n_j - 2*(A A^T)_ij, 0)), stored u16
//      q0 = min(floor(d*qscale), 65535), qscale 1024 (x) / 2048 (z).
//   3. rank kernel (counting, fused x+z, single atomic pass): per row
//      normalize q0 to 11-bit bins; ONE ds_add_rtn pass counts AND yields
//      intra-bin offsets (kept in 16 packed VGPRs); dual scan; final pass
//      is plain ds_read: rank = scanned_base + offset; |rx-rz| inline.
//      32 LDS atomics/thread (round 5: 64 — the dominant cost).
//   4. finalize: 3 scalars.

#define N 4096
#define DX 512
#define DZ 64
#define NBIN 2048          // 11-bit normalized bins
#define NWRD (NBIN / 2)    // u16-packed pairs -> 1024 u32 words per hist

typedef __attribute__((ext_vector_type(8))) short short8;
typedef __attribute__((ext_vector_type(4))) float float4v;

// ---------------- async 16B global -> LDS ----------------
__device__ __forceinline__ void async16(const void* g, void* l) {
  __builtin_amdgcn_global_load_lds(
      (const __attribute__((address_space(1))) unsigned int*)(g),
      (__attribute__((address_space(3))) unsigned int*)(l), 16, 0, 0);
}

// ---------------- prep: norms + bf16 casts ----------------
__global__ __launch_bounds__(256) void prep_kernel(
    const float* __restrict__ x, const float* __restrict__ z,
    __hip_bfloat16* __restrict__ xb, __hip_bfloat16* __restrict__ zb,
    float* __restrict__ nx, float* __restrict__ nz) {
  int row = blockIdx.x;
  int tid = threadIdx.x;
  __shared__ float red[256];

  float sx = 0.f;
  for (int c = tid; c < DX; c += 256) {
    float v = x[(size_t)row * DX + c];
    xb[(size_t)row * DX + c] = __float2bfloat16(v);
    sx += v * v;
  }
  red[tid] = sx;
  __syncthreads();
  for (int s = 128; s > 0; s >>= 1) {
    if (tid < s) red[tid] += red[tid + s];
    __syncthreads();
  }
  if (tid == 0) nx[row] = red[0];
  __syncthreads();

  float sz = 0.f;
  if (tid < DZ) {
    float v = z[(size_t)row * DZ + tid];
    zb[(size_t)row * DZ + tid] = __float2bfloat16(v);
    sz = v * v;
  }
  red[tid] = sz;
  __syncthreads();
  for (int s = 128; s > 0; s >>= 1) {
    if (tid < s) red[tid] += red[tid + s];
    __syncthreads();
  }
  if (tid == 0) nz[row] = red[0];
}

// ---------------- bf16 MFMA Gram + quantized-distance epilogue ----------
#define TILE 128
#define BK 32

__global__ __launch_bounds__(256) void gram_dist_kernel(
    const __hip_bfloat16* __restrict__ Abf, const float* __restrict__ norms,
    unsigned short* __restrict__ distq, int K, float qscale) {
  __shared__ short As[TILE * BK];  // 8 KB, row-major [128][32]
  __shared__ short Bs[TILE * BK];

  int tid = threadIdx.x;
  int wave = tid >> 6, lane = tid & 63;
  int wr = wave >> 1, wc = wave & 1;
  int quad = lane >> 4, l15 = lane & 15;

  int rowBase = blockIdx.y * TILE;
  int colBase = blockIdx.x * TILE;

  float4v acc[4][4];
#pragma unroll
  for (int mi = 0; mi < 4; ++mi)
#pragma unroll
    for (int ni = 0; ni < 4; ++ni) {
      float4v zv = {0.f, 0.f, 0.f, 0.f};
      acc[mi][ni] = zv;
    }

  const char* Ab = (const char*)Abf;
  const size_t rb = (size_t)K * 2;  // row bytes
  int chunk0 = wave * 2, chunk1 = wave * 2 + 1;
  int rl = lane >> 2;        // row within a 16-row chunk (4 lanes/row)
  int cl = (lane & 3) * 16;  // byte col within 64B row

  for (int kc = 0; kc < K; kc += BK) {
    const char* base = Ab + (size_t)kc * 2 + cl;
    async16(base + (size_t)(rowBase + chunk0 * 16 + rl) * rb,
            &As[chunk0 * 512]);
    async16(base + (size_t)(rowBase + chunk1 * 16 + rl) * rb,
            &As[chunk1 * 512]);
    async16(base + (size_t)(colBase + chunk0 * 16 + rl) * rb,
            &Bs[chunk0 * 512]);
    async16(base + (size_t)(colBase + chunk1 * 16 + rl) * rb,
            &Bs[chunk1 * 512]);
    __syncthreads();

    short8 a[4], b[4];
#pragma unroll
    for (int mi = 0; mi < 4; ++mi)
      a[mi] = *(const short8*)(&As[(wr * 64 + mi * 16 + l15) * BK + quad * 8]);
#pragma unroll
    for (int ni = 0; ni < 4; ++ni)
      b[ni] = *(const short8*)(&Bs[(wc * 64 + ni * 16 + l15) * BK + quad * 8]);
#pragma unroll
    for (int mi = 0; mi < 4; ++mi)
#pragma unroll
      for (int ni = 0; ni < 4; ++ni)
        acc[mi][ni] = __builtin_amdgcn_mfma_f32_16x16x32_bf16(
            a[mi], b[ni], acc[mi][ni], 0, 0, 0);
    __syncthreads();
  }

#pragma unroll
  for (int mi = 0; mi < 4; ++mi) {
#pragma unroll
    for (int ni = 0; ni < 4; ++ni) {
      int col = colBase + wc * 64 + ni * 16 + l15;
      float ncol = norms[col];
#pragma unroll
      for (int r = 0; r < 4; ++r) {
        int row = rowBase + wr * 64 + mi * 16 + quad * 4 + r;
        float sq = norms[row] + ncol - 2.0f * acc[mi][ni][r];
        float d = sq > 0.f ? sqrtf(sq) : 0.f;
        if (row == col) d = 0.f;
        unsigned q = (unsigned)(d * qscale);
        distq[(size_t)row * N + col] =
            (unsigned short)(q > 65535u ? 65535u : q);
      }
    }
  }
}

// ---------------- fused counting-based per-row ranks ----------------
// Word-index swizzle (bijective per 32-word block): sequential per-thread
// scan accesses become low-way bank aliasing instead of 16/32-way.
__device__ __forceinline__ int hsw(int w) { return w ^ ((w >> 5) & 31); }

__global__ __launch_bounds__(256) void rank_kernel(
    const unsigned short* __restrict__ qx,
    const unsigned short* __restrict__ qz,
    unsigned long long* __restrict__ rank_acc, double* __restrict__ pd_acc) {
  __shared__ unsigned histX[NWRD];  // 4 KB
  __shared__ unsigned histZ[NWRD];  // 4 KB
  __shared__ unsigned xch[32];

  int t = threadIdx.x, row = blockIdx.x;
  int lane = t & 63, wv = t >> 6;
  const uint4* px = (const uint4*)(qx + (size_t)row * N);
  const uint4* pz = (const uint4*)(qz + (size_t)row * N);

  // ---- load my 16 x and 16 z values; keep resident (16 VGPRs) ----
  uint4 xa = px[t * 2], xb4 = px[t * 2 + 1];
  uint4 za = pz[t * 2], zb4 = pz[t * 2 + 1];
  unsigned xw[8] = {xa.x, xa.y, xa.z, xa.w, xb4.x, xb4.y, xb4.z, xb4.w};
  unsigned zw[8] = {za.x, za.y, za.z, za.w, zb4.x, zb4.y, zb4.z, zb4.w};

  // zero both hists (no dependency on loads)
#pragma unroll
  for (int i = 0; i < 4; ++i) {
    histX[t + 256 * i] = 0u;
    histZ[t + 256 * i] = 0u;
  }

  // ---- pairdist partial + per-row off-diagonal min / max ----
  float pd = 0.f;
  unsigned mnx = 65535u, mxx = 0u, mnz = 65535u, mxz = 0u;
#pragma unroll
  for (int c = 0; c < 16; ++c) {
    unsigned qxv = (xw[c >> 1] >> ((c & 1) * 16)) & 0xFFFFu;
    unsigned qzv = (zw[c >> 1] >> ((c & 1) * 16)) & 0xFFFFu;
    // dz-dx = ((qz+.5)/2048 - (qx+.5)/1024) = (qz - 2*qx - 0.5)/2048
    float tt = (float)(int)qzv - 2.0f * (float)(int)qxv - 0.5f;
    pd += tt * tt;
    bool diag = (t * 16 + c) == row;
    mnx = min(mnx, diag ? 65535u : qxv);
    mnz = min(mnz, diag ? 65535u : qzv);
    mxx = max(mxx, qxv);
    mxz = max(mxz, qzv);
  }
#pragma unroll
  for (int d = 32; d; d >>= 1) {
    mnx = min(mnx, (unsigned)__shfl_xor((int)mnx, d, 64));
    mxx = max(mxx, (unsigned)__shfl_xor((int)mxx, d, 64));
    mnz = min(mnz, (unsigned)__shfl_xor((int)mnz, d, 64));
    mxz = max(mxz, (unsigned)__shfl_xor((int)mxz, d, 64));
  }
  if (lane == 0) {
    xch[wv * 4 + 0] = mnx;
    xch[wv * 4 + 1] = mxx;
    xch[wv * 4 + 2] = mnz;
    xch[wv * 4 + 3] = mxz;
  }
  __syncthreads();  // covers hist zeroing + minmax exchange
  unsigned fmnx = min(min(xch[0], xch[4]), min(xch[8], xch[12]));
  unsigned fmxx = max(max(xch[1], xch[5]), max(xch[9], xch[13]));
  unsigned fmnz = min(min(xch[2], xch[6]), min(xch[10], xch[14]));
  unsigned fmxz = max(max(xch[3], xch[7]), max(xch[11], xch[15]));

  float lox = (float)(int)fmnx;
  float scx = (float)(NBIN - 1) / (float)(int)(fmxx > fmnx ? fmxx - fmnx : 1u);
  float loz = (float)(int)fmnz;
  float scz = (float)(NBIN - 1) / (float)(int)(fmxz > fmnz ? fmxz - fmnz : 1u);

  // ---- single atomic pass: count AND capture intra-bin offset ----
  unsigned oxp[8], ozp[8];
#pragma unroll
  for (int c = 0; c < 16; ++c) {
    unsigned qxv = (xw[c >> 1] >> ((c & 1) * 16)) & 0xFFFFu;
    unsigned qzv = (zw[c >> 1] >> ((c & 1) * 16)) & 0xFFFFu;
    unsigned bx = (unsigned)(int)fminf(
        fmaxf(((float)(int)qxv - lox) * scx, 0.0f), (float)(NBIN - 1));
    unsigned bz = (unsigned)(int)fminf(
        fmaxf(((float)(int)qzv - loz) * scz, 0.0f), (float)(NBIN - 1));
    unsigned shx = (bx & 1) * 16, shz = (bz & 1) * 16;
    unsigned ox =
        (atomicAdd(&histX[hsw((int)(bx >> 1))], 1u << shx) >> shx) & 0xFFFFu;
    unsigned oz =
        (atomicAdd(&histZ[hsw((int)(bz >> 1))], 1u << shz) >> shz) & 0xFFFFu;
    if (c & 1) {
      oxp[c >> 1] |= ox << 16;
      ozp[c >> 1] |= oz << 16;
    } else {
      oxp[c >> 1] = ox;
      ozp[c >> 1] = oz;
    }
  }
  __syncthreads();

  // ---- dual exclusive scan: waves 0-1 -> histX, waves 2-3 -> histZ ----
  {
    unsigned* h = (t < 128) ? histX : histZ;
    int tt = t & 127;
    int wb = tt * 8;
    unsigned run = 0;
#pragma unroll
    for (int c = 0; c < 8; ++c) {
      int w = hsw(wb + c);
      unsigned v = h[w];
      unsigned lo = v & 0xFFFFu;
      h[w] = run | ((run + lo) << 16);
      run += lo + (v >> 16);
    }
    unsigned incl = run;
#pragma unroll
    for (int d = 1; d < 64; d <<= 1) {
      unsigned o = (unsigned)__shfl_up((int)incl, d, 64);
      if (lane >= d) incl += o;
    }
    if (lane == 63) xch[16 + wv] = incl;
    __syncthreads();
    unsigned base = incl - run;               // exclusive within my wave
    if (wv & 1) base += xch[16 + (wv - 1)];   // add lower wave of my hist
    unsigned add = base * 0x10001u;
#pragma unroll
    for (int c = 0; c < 8; ++c) h[hsw(wb + c)] += add;
  }
  __syncthreads();

  // ---- final pass: plain ds_read of scanned bases; |rx-rz| inline ----
  int rsum = 0;
#pragma unroll
  for (int c = 0; c < 16; ++c) {
    unsigned qxv = (xw[c >> 1] >> ((c & 1) * 16)) & 0xFFFFu;
    unsigned qzv = (zw[c >> 1] >> ((c & 1) * 16)) & 0xFFFFu;
    unsigned bx = (unsigned)(int)fminf(
        fmaxf(((float)(int)qxv - lox) * scx, 0.0f), (float)(NBIN - 1));
    unsigned bz = (unsigned)(int)fminf(
        fmaxf(((float)(int)qzv - loz) * scz, 0.0f), (float)(NBIN - 1));
    unsigned shx = (bx & 1) * 16, shz = (bz & 1) * 16;
    unsigned basex = (histX[hsw((int)(bx >> 1))] >> shx) & 0xFFFFu;
    unsigned basez = (histZ[hsw((int)(bz >> 1))] >> shz) & 0xFFFFu;
    int rx = (int)(basex + ((oxp[c >> 1] >> ((c & 1) * 16)) & 0xFFFFu));
    int rz = (int)(basez + ((ozp[c >> 1] >> ((c & 1) * 16)) & 0xFFFFu));
    int d = rx - rz;
    rsum += d < 0 ? -d : d;
  }

  // ---- block reduce + global atomics ----
#pragma unroll
  for (int d = 32; d; d >>= 1) {
    rsum += __shfl_xor(rsum, d, 64);
    pd += __shfl_xor(pd, d, 64);
  }
  if (lane == 0) {
    xch[wv] = (unsigned)rsum;
    ((float*)xch)[8 + wv] = pd;
  }
  __syncthreads();
  if (t == 0) {
    unsigned long long rtot =
        (unsigned long long)xch[0] + xch[1] + xch[2] + xch[3];
    float ptot = ((float*)xch)[8] + ((float*)xch)[9] + ((float*)xch)[10] +
                 ((float*)xch)[11];
    atomicAdd(rank_acc, rtot);
    atomicAdd(pd_acc, (double)ptot);
  }
}

// ---------------- finalize ----------------
__global__ void finalize_kernel(const unsigned long long* __restrict__ racc,
                                const double* __restrict__ pacc,
                                float* __restrict__ out) {
  double inv = 1.0 / ((double)N * (double)N);
  double rank_loss = (double)(*racc) * inv / 32.0;  // K = 32
  double pd = (*pacc) * inv / (2048.0 * 2048.0);    // undo q scaling
  out[0] = (float)(rank_loss + 0.5 * pd);
  out[1] = (float)rank_loss;
  out[2] = (float)pd;
}

// ---------------- launch ----------------
extern "C" void kernel_launch(void* const* d_in, const int* in_sizes, int n_in,
                              void* d_out, int out_size, void* d_ws,
                              size_t ws_size, hipStream_t stream) {
  (void)in_sizes; (void)n_in; (void)out_size; (void)ws_size;
  const float* x = (const float*)d_in[0];
  const float* z = (const float*)d_in[1];
  float* out = (float*)d_out;

  char* w = (char*)d_ws;
  unsigned short* qx16 = (unsigned short*)(w);             // 32 MB
  unsigned short* qz16 = (unsigned short*)(w + 33554432);  // 32 MB
  __hip_bfloat16* xb = (__hip_bfloat16*)(w + 67108864);    // 4 MB
  __hip_bfloat16* zb = (__hip_bfloat16*)(w + 71303168);    // 0.5 MB
  float* nx = (float*)(w + 71827456);
  float* nz = (float*)(w + 71843840);
  unsigned long long* rank_acc = (unsigned long long*)(w + 71860224);
  double* pd_acc = (double*)(w + 71860232);

  hipMemsetAsync(w + 71860224, 0, 16, stream);

  prep_kernel<<<N, 256, 0, stream>>>(x, z, xb, zb, nx, nz);

  dim3 ggrid(N / TILE, N / TILE);
  gram_dist_kernel<<<ggrid, 256, 0, stream>>>(xb, nx, qx16, DX, 1024.0f);
  gram_dist_kernel<<<ggrid, 256, 0, stream>>>(zb, nz, qz16, DZ, 2048.0f);

  rank_kernel<<<N, 256, 0, stream>>>(qx16, qz16, rank_acc, pd_acc);

  finalize_kernel<<<1, 1, 0, stream>>>(rank_acc, pd_acc, out);
}